// Round 1
// baseline (269.031 us; speedup 1.0000x reference)
//
#include <hip/hip_runtime.h>

#define N_NODES 50000
#define N_EDGES 800000
#define DIM     64

// out[n][d] = b[d]  (bias pre-fill; scatter accumulates on top)
__global__ __launch_bounds__(256) void init_out_kernel(const float* __restrict__ b,
                                                       float* __restrict__ out,
                                                       int total) {
    int i = blockIdx.x * blockDim.x + threadIdx.x;
    if (i < total) out[i] = b[i & (DIM - 1)];
}

// support = X @ W.  X:[N,64] W:[64,64].  16 rows per block, 256 threads.
// Thread (r0 = tid>>6, col = tid&63) computes rows {r0, r0+4, r0+8, r0+12}.
// sW[k*64+col]: 64 consecutive floats per k -> 2-way bank aliasing (free on CDNA4).
// sX[row*64+k]: same address across the 64 lanes of a wave -> broadcast (free).
__global__ __launch_bounds__(256) void gemm_xw_kernel(const float* __restrict__ X,
                                                      const float* __restrict__ W,
                                                      float* __restrict__ support) {
    __shared__ float sW[DIM * DIM];   // 16 KB
    __shared__ float sX[16 * DIM];    // 4 KB
    const int tid = threadIdx.x;

    for (int i = tid; i < DIM * DIM; i += 256) sW[i] = W[i];

    const int rowBase = blockIdx.x * 16;          // 50000 = 16 * 3125, exact
    for (int i = tid; i < 16 * DIM; i += 256)
        sX[i] = X[(rowBase + (i >> 6)) * DIM + (i & (DIM - 1))];

    __syncthreads();

    const int col = tid & (DIM - 1);
    const int r0  = tid >> 6;                     // 0..3
    float acc0 = 0.f, acc1 = 0.f, acc2 = 0.f, acc3 = 0.f;
    #pragma unroll
    for (int k = 0; k < DIM; ++k) {
        const float w = sW[k * DIM + col];
        acc0 += sX[(r0     ) * DIM + k] * w;
        acc1 += sX[(r0 +  4) * DIM + k] * w;
        acc2 += sX[(r0 +  8) * DIM + k] * w;
        acc3 += sX[(r0 + 12) * DIM + k] * w;
    }
    const int r = rowBase + r0;
    support[(r     ) * DIM + col] = acc0;
    support[(r +  4) * DIM + col] = acc1;
    support[(r +  8) * DIM + col] = acc2;
    support[(r + 12) * DIM + col] = acc3;
}

// One wave per edge; lane = feature.  Coalesced 256B row gather (L2-resident),
// 64 coalesced fp32 atomics into out[dst].
__global__ __launch_bounds__(256) void scatter_kernel(const int*   __restrict__ edge_src,
                                                      const int*   __restrict__ edge_dst,
                                                      const float* __restrict__ edge_weight,
                                                      const float* __restrict__ support,
                                                      float* __restrict__ out) {
    const int e    = (blockIdx.x * blockDim.x + threadIdx.x) >> 6;
    const int lane = threadIdx.x & 63;
    if (e < N_EDGES) {
        const int   s  = edge_src[e];
        const int   d  = edge_dst[e];
        const float wt = edge_weight[e];
        const float v  = wt * support[s * DIM + lane];
        atomicAdd(&out[d * DIM + lane], v);
    }
}

extern "C" void kernel_launch(void* const* d_in, const int* in_sizes, int n_in,
                              void* d_out, int out_size, void* d_ws, size_t ws_size,
                              hipStream_t stream) {
    const float* X           = (const float*)d_in[0];
    const int*   edge_src    = (const int*)  d_in[1];
    const int*   edge_dst    = (const int*)  d_in[2];
    const float* edge_weight = (const float*)d_in[3];
    const float* W           = (const float*)d_in[4];
    const float* b           = (const float*)d_in[5];
    float*       out         = (float*)d_out;
    float*       support     = (float*)d_ws;          // 50000*64*4 = 12.8 MB

    // 1) out = broadcast(b)
    {
        const int total  = N_NODES * DIM;             // 3.2M
        const int blocks = (total + 255) / 256;
        hipLaunchKernelGGL(init_out_kernel, dim3(blocks), dim3(256), 0, stream,
                           b, out, total);
    }
    // 2) support = X @ W
    {
        const int blocks = N_NODES / 16;              // 3125
        hipLaunchKernelGGL(gemm_xw_kernel, dim3(blocks), dim3(256), 0, stream,
                           X, W, support);
    }
    // 3) out[dst] += w_e * support[src]
    {
        const long long threads = (long long)N_EDGES * 64;
        const int blocks = (int)((threads + 255) / 256); // 200000
        hipLaunchKernelGGL(scatter_kernel, dim3(blocks), dim3(256), 0, stream,
                           edge_src, edge_dst, edge_weight, support, out);
    }
}